// Round 4
// baseline (46.573 us; speedup 1.0000x reference)
//
#include <hip/hip_runtime.h>

#define NCLS 10
#define IGN 10
#define HW_ (512 * 512)          // 262144 = 2^18
#define BATCH 8
#define NPIX (BATCH * HW_)       // 2097152
#define THREADS 256
#define PIXPERTHREAD 4
#define CHUNKS 2
#define NBLOCKS (NPIX / (THREADS * PIXPERTHREAD * CHUNKS))  // 1024
#define STAT_STRIDE 16
#define LAMBDA_UNC 0.5f
#define LOG2E 1.4426950408889634f
#define LN2 0.6931471805599453f

// LDS histogram geometry: 4 waves x 8 copies = 32 regions, stride 37 floats
// (37%32=5, coprime with 32 -> regions land on distinct banks).
#define NREGION 32
#define RSTRIDE 37
#define HISTSZ (NREGION * RSTRIDE)   // 1184 floats = 4736 B

__global__ void awce_zero_stats(float* __restrict__ stats) {
    int i = threadIdx.x;
    if (i < 30 * STAT_STRIDE) stats[i] = 0.0f;
}

template <bool ATOMIC>
__global__ __launch_bounds__(THREADS, 4) void awce_main(
    const float* __restrict__ logits,
    const int* __restrict__ targets,
    float* __restrict__ outbuf)
{
    const int tid = threadIdx.x;

    __shared__ float hist[HISTSZ];
#pragma unroll
    for (int i = 0; i < (HISTSZ + THREADS - 1) / THREADS; ++i) {
        const int idx = tid + i * THREADS;
        if (idx < HISTSZ) hist[idx] = 0.0f;
    }
    __syncthreads();

    // this thread's histogram region: wave (tid>>6) * 8 copies + (tid>>3)&7
    const int region = ((tid >> 6) << 3) | ((tid >> 3) & 7);
    float* hreg = &hist[region * RSTRIDE];

    // Double-buffered registers: 2 x (10 channels x 4 pixels) + targets.
    float xb_[2][NCLS][4];
    int tb_[2][4];

    auto chunk_p0 = [&](int k) {
        return ((blockIdx.x * CHUNKS + k) * THREADS + tid) * PIXPERTHREAD;
    };

#define LOAD_CHUNK(k, slot)                                                        \
    {                                                                              \
        const int p0 = chunk_p0(k);                                                \
        const int b = p0 >> 18;                                                    \
        const int hw = p0 & (HW_ - 1);                                             \
        const float* base = logits + (size_t)b * (NCLS * (size_t)HW_) + hw;        \
        _Pragma("unroll")                                                          \
        for (int c = 0; c < NCLS; ++c) {                                           \
            float4 v = *reinterpret_cast<const float4*>(base + (size_t)c * HW_);   \
            xb_[slot][c][0] = v.x; xb_[slot][c][1] = v.y;                          \
            xb_[slot][c][2] = v.z; xb_[slot][c][3] = v.w;                          \
        }                                                                          \
        int4 t4 = *reinterpret_cast<const int4*>(targets + p0);                    \
        tb_[slot][0] = t4.x; tb_[slot][1] = t4.y;                                  \
        tb_[slot][2] = t4.z; tb_[slot][3] = t4.w;                                  \
    }

#define PROC_CHUNK(slot)                                                           \
    {                                                                              \
        _Pragma("unroll")                                                          \
        for (int j = 0; j < PIXPERTHREAD; ++j) {                                   \
            const int tj = tb_[slot][j];                                           \
            const bool valid = (tj != IGN);                                        \
            const int tc = valid ? tj : (NCLS - 1);                                \
            float m = xb_[slot][0][j];                                             \
            _Pragma("unroll")                                                      \
            for (int c = 1; c < NCLS; ++c) m = fmaxf(m, xb_[slot][c][j]);          \
            const float nm2 = -m * LOG2E;                                          \
            float s = 0.f, dot = 0.f, xt = 0.f;                                    \
            _Pragma("unroll")                                                      \
            for (int c = 0; c < NCLS; ++c) {                                       \
                const float xc = xb_[slot][c][j];                                  \
                const float e = __builtin_amdgcn_exp2f(fmaf(xc, LOG2E, nm2));      \
                s += e;                                                            \
                dot = fmaf(e, xc, dot);                                            \
                xt = (tc == c) ? xc : xt;                                          \
            }                                                                      \
            const float lse = fmaf(__builtin_amdgcn_logf(s), LN2, m);              \
            const float rs = __builtin_amdgcn_rcpf(s);                             \
            const float ent = fmaf(-dot, rs, lse);                                 \
            const float ce = lse - xt;                                             \
            if (valid) {                                                           \
                atomicAdd(&hreg[tc], 1.0f);                                        \
                atomicAdd(&hreg[10 + tc], ent);                                    \
                atomicAdd(&hreg[20 + tc], ce);                                     \
            }                                                                      \
        }                                                                          \
    }

    LOAD_CHUNK(0, 0)
    LOAD_CHUNK(1, 1)
    PROC_CHUNK(0)
    PROC_CHUNK(1)
#undef LOAD_CHUNK
#undef PROC_CHUNK

    __syncthreads();

    // Reduce 32 regions -> 30 stats. Lanes 0..29 read addr r*37+tid:
    // banks (5r+tid)%32, conflict-free per iteration.
    if (tid < 30) {
        float v = 0.f;
#pragma unroll
        for (int r = 0; r < NREGION; ++r) v += hist[r * RSTRIDE + tid];
        if (ATOMIC) {
            atomicAdd(&outbuf[tid * STAT_STRIDE], v);
        } else {
            outbuf[tid * NBLOCKS + blockIdx.x] = v;
        }
    }
}

// Reduce 30 x NBLOCKS partials, compute final loss. One block, 512 threads.
__global__ __launch_bounds__(512) void awce_final_partials(
    const float* __restrict__ partials, float* __restrict__ out)
{
    __shared__ float sred[32];
    const int wave = threadIdx.x >> 6;
    const int lane = threadIdx.x & 63;
#pragma unroll
    for (int k = 0; k < 4; ++k) {
        const int c = wave + k * 8;
        if (c < 30) {
            const float* col = partials + (size_t)c * NBLOCKS;
            float s = 0.f;
#pragma unroll
            for (int i = 0; i < NBLOCKS / 64; ++i) s += col[lane + 64 * i];
#pragma unroll
            for (int o = 32; o >= 1; o >>= 1) s += __shfl_xor(s, o);
            if (lane == 0) sred[c] = s;
        }
    }
    __syncthreads();
    if (threadIdx.x == 0) {
        float cnt[NCLS], es[NCLS], cs[NCLS];
        float nv = 0.f;
#pragma unroll
        for (int c = 0; c < NCLS; ++c) {
            cnt[c] = sred[c];
            es[c]  = sred[10 + c];
            cs[c]  = sred[20 + c];
            nv += cnt[c];
        }
        float loss = 0.f;
#pragma unroll
        for (int c = 0; c < NCLS; ++c) {
            float wb = 0.f;
            if (cnt[c] > 0.f && nv > 0.f) wb = (nv - cnt[c]) / fmaxf(nv, 1.f);
            const float em = (cnt[c] > 0.f) ? es[c] / fmaxf(cnt[c], 1.f) : 0.f;
            const float wc = wb * (1.f + LAMBDA_UNC * em);
            loss = fmaf(cs[c], wc, loss);
        }
        out[0] = loss / (nv + 1e-6f);
    }
}

__global__ void awce_final_atomic(const float* __restrict__ stats, float* __restrict__ out) {
    if (threadIdx.x == 0) {
        float cnt[NCLS], es[NCLS], cs[NCLS];
        float nv = 0.f;
#pragma unroll
        for (int c = 0; c < NCLS; ++c) {
            cnt[c] = stats[c * STAT_STRIDE];
            es[c]  = stats[(10 + c) * STAT_STRIDE];
            cs[c]  = stats[(20 + c) * STAT_STRIDE];
            nv += cnt[c];
        }
        float loss = 0.f;
#pragma unroll
        for (int c = 0; c < NCLS; ++c) {
            float wb = 0.f;
            if (cnt[c] > 0.f && nv > 0.f) wb = (nv - cnt[c]) / fmaxf(nv, 1.f);
            const float em = (cnt[c] > 0.f) ? es[c] / fmaxf(cnt[c], 1.f) : 0.f;
            const float wc = wb * (1.f + LAMBDA_UNC * em);
            loss = fmaf(cs[c], wc, loss);
        }
        out[0] = loss / (nv + 1e-6f);
    }
}

extern "C" void kernel_launch(void* const* d_in, const int* in_sizes, int n_in,
                              void* d_out, int out_size, void* d_ws, size_t ws_size,
                              hipStream_t stream) {
    const float* logits = (const float*)d_in[0];
    const int* targets = (const int*)d_in[1];
    float* out = (float*)d_out;
    float* ws = (float*)d_ws;

    const size_t need = (size_t)30 * NBLOCKS * sizeof(float);   // 122,880 B
    if (ws_size >= need) {
        awce_main<false><<<NBLOCKS, THREADS, 0, stream>>>(logits, targets, ws);
        awce_final_partials<<<1, 512, 0, stream>>>(ws, out);
    } else {
        awce_zero_stats<<<1, 512, 0, stream>>>(ws);
        awce_main<true><<<NBLOCKS, THREADS, 0, stream>>>(logits, targets, ws);
        awce_final_atomic<<<1, 64, 0, stream>>>(ws, out);
    }
}

// Round 5
// 26.067 us; speedup vs baseline: 1.7866x; 1.7866x over previous
//
#include <hip/hip_runtime.h>

#define NCLS 10
#define IGN 10
#define HW_ (512 * 512)          // 262144 = 2^18
#define BATCH 8
#define NPIX (BATCH * HW_)       // 2097152
#define THREADS 256
#define PIXPERTHREAD 4
#define CHUNKS 2
#define NBLOCKS (NPIX / (THREADS * PIXPERTHREAD * CHUNKS))  // 1024
#define STAT_STRIDE 16
#define LAMBDA_UNC 0.5f
#define LOG2E 1.4426950408889634f
#define LN2 0.6931471805599453f

// Per-thread private LDS histogram region: 33 floats (30 stats + 3 dump
// slots for ignore-index pixels). Stride 33 ≡ 1 (mod 32): region r, offset o
// lands on bank (r+o)%32 -> offsets spread across banks, no atomic needed.
#define RSTRIDE 33
#define HISTSZ (THREADS * RSTRIDE)   // 8448 floats = 33792 B

__global__ void awce_zero_stats(float* __restrict__ stats) {
    int i = threadIdx.x;
    if (i < 30 * STAT_STRIDE) stats[i] = 0.0f;
}

template <bool ATOMIC>
__global__ __launch_bounds__(THREADS, 4) void awce_main(
    const float* __restrict__ logits,
    const int* __restrict__ targets,
    float* __restrict__ outbuf)
{
    const int tid = threadIdx.x;

    __shared__ float hist[HISTSZ];
    __shared__ float red[4][32];
#pragma unroll
    for (int i = 0; i < RSTRIDE; ++i) hist[tid + i * THREADS] = 0.0f;
    __syncthreads();

    float* hreg = &hist[tid * RSTRIDE];

    // Double-buffered registers: 2 x (10 channels x 4 pixels) + targets.
    float xb_[2][NCLS][4];
    int tb_[2][4];

    auto chunk_p0 = [&](int k) {
        return ((blockIdx.x * CHUNKS + k) * THREADS + tid) * PIXPERTHREAD;
    };

#define LOAD_CHUNK(k, slot)                                                        \
    {                                                                              \
        const int p0 = chunk_p0(k);                                                \
        const int b = p0 >> 18;                                                    \
        const int hw = p0 & (HW_ - 1);                                             \
        const float* base = logits + (size_t)b * (NCLS * (size_t)HW_) + hw;        \
        _Pragma("unroll")                                                          \
        for (int c = 0; c < NCLS; ++c) {                                           \
            float4 v = *reinterpret_cast<const float4*>(base + (size_t)c * HW_);   \
            xb_[slot][c][0] = v.x; xb_[slot][c][1] = v.y;                          \
            xb_[slot][c][2] = v.z; xb_[slot][c][3] = v.w;                          \
        }                                                                          \
        int4 t4 = *reinterpret_cast<const int4*>(targets + p0);                    \
        tb_[slot][0] = t4.x; tb_[slot][1] = t4.y;                                  \
        tb_[slot][2] = t4.z; tb_[slot][3] = t4.w;                                  \
    }

// Per pixel: softmax stats in registers, then 3 plain LDS RMWs into the
// thread's PRIVATE region at runtime offset 3*tc (+0 cnt, +1 ent, +2 ce).
// Invalid pixels (tj==IGN) use tc=NCLS -> offsets 30..32 (dump slots).
#define PROC_CHUNK(slot)                                                           \
    {                                                                              \
        _Pragma("unroll")                                                          \
        for (int j = 0; j < PIXPERTHREAD; ++j) {                                   \
            const int tj = tb_[slot][j];                                           \
            const int tc = (tj != IGN) ? tj : NCLS;                                \
            float m = xb_[slot][0][j];                                             \
            _Pragma("unroll")                                                      \
            for (int c = 1; c < NCLS; ++c) m = fmaxf(m, xb_[slot][c][j]);          \
            const float nm2 = -m * LOG2E;                                          \
            float s = 0.f, dot = 0.f, xt = 0.f;                                    \
            _Pragma("unroll")                                                      \
            for (int c = 0; c < NCLS; ++c) {                                       \
                const float xc = xb_[slot][c][j];                                  \
                const float e = __builtin_amdgcn_exp2f(fmaf(xc, LOG2E, nm2));      \
                s += e;                                                            \
                dot = fmaf(e, xc, dot);                                            \
                xt = (tc == c) ? xc : xt;                                          \
            }                                                                      \
            const float lse = fmaf(__builtin_amdgcn_logf(s), LN2, m);              \
            const float rs = __builtin_amdgcn_rcpf(s);                             \
            const float ent = fmaf(-dot, rs, lse);                                 \
            const float ce = lse - xt;                                             \
            float* p = hreg + 3 * tc;                                              \
            p[0] += 1.0f;                                                          \
            p[1] += ent;                                                           \
            p[2] += ce;                                                            \
        }                                                                          \
    }

    LOAD_CHUNK(0, 0)
    LOAD_CHUNK(1, 1)
    __builtin_amdgcn_sched_barrier(0);   // don't sink chunk-1 loads into PROC(0)
    PROC_CHUNK(0)
    PROC_CHUNK(1)
#undef LOAD_CHUNK
#undef PROC_CHUNK

    __syncthreads();

    // Stage 1: each wave reduces its 64 regions. Lane o<30: class c=o%10,
    // field f=o/10, region offset 3c+f (unique 0..29 -> distinct banks).
    const int wave = tid >> 6;
    const int lane = tid & 63;
    if (lane < 30) {
        const int f = (lane >= 20) ? 2 : ((lane >= 10) ? 1 : 0);
        const int c = lane - f * 10;
        const int off = 3 * c + f;
        float v = 0.f;
#pragma unroll
        for (int r = 0; r < 64; ++r) v += hist[(wave * 64 + r) * RSTRIDE + off];
        red[wave][lane] = v;
    }
    __syncthreads();

    // Stage 2: combine 4 wave-partials; stat index = f*10+c = lane.
    if (tid < 30) {
        float v = red[0][tid] + red[1][tid] + red[2][tid] + red[3][tid];
        if (ATOMIC) {
            atomicAdd(&outbuf[tid * STAT_STRIDE], v);
        } else {
            outbuf[tid * NBLOCKS + blockIdx.x] = v;
        }
    }
}

// Reduce 30 x NBLOCKS partials, compute final loss. One block, 512 threads.
__global__ __launch_bounds__(512) void awce_final_partials(
    const float* __restrict__ partials, float* __restrict__ out)
{
    __shared__ float sred[32];
    const int wave = threadIdx.x >> 6;
    const int lane = threadIdx.x & 63;
#pragma unroll
    for (int k = 0; k < 4; ++k) {
        const int c = wave + k * 8;
        if (c < 30) {
            const float* col = partials + (size_t)c * NBLOCKS;
            float s = 0.f;
#pragma unroll
            for (int i = 0; i < NBLOCKS / 64; ++i) s += col[lane + 64 * i];
#pragma unroll
            for (int o = 32; o >= 1; o >>= 1) s += __shfl_xor(s, o);
            if (lane == 0) sred[c] = s;
        }
    }
    __syncthreads();
    if (threadIdx.x == 0) {
        float cnt[NCLS], es[NCLS], cs[NCLS];
        float nv = 0.f;
#pragma unroll
        for (int c = 0; c < NCLS; ++c) {
            cnt[c] = sred[c];
            es[c]  = sred[10 + c];
            cs[c]  = sred[20 + c];
            nv += cnt[c];
        }
        float loss = 0.f;
#pragma unroll
        for (int c = 0; c < NCLS; ++c) {
            float wb = 0.f;
            if (cnt[c] > 0.f && nv > 0.f) wb = (nv - cnt[c]) / fmaxf(nv, 1.f);
            const float em = (cnt[c] > 0.f) ? es[c] / fmaxf(cnt[c], 1.f) : 0.f;
            const float wc = wb * (1.f + LAMBDA_UNC * em);
            loss = fmaf(cs[c], wc, loss);
        }
        out[0] = loss / (nv + 1e-6f);
    }
}

__global__ void awce_final_atomic(const float* __restrict__ stats, float* __restrict__ out) {
    if (threadIdx.x == 0) {
        float cnt[NCLS], es[NCLS], cs[NCLS];
        float nv = 0.f;
#pragma unroll
        for (int c = 0; c < NCLS; ++c) {
            cnt[c] = stats[c * STAT_STRIDE];
            es[c]  = stats[(10 + c) * STAT_STRIDE];
            cs[c]  = stats[(20 + c) * STAT_STRIDE];
            nv += cnt[c];
        }
        float loss = 0.f;
#pragma unroll
        for (int c = 0; c < NCLS; ++c) {
            float wb = 0.f;
            if (cnt[c] > 0.f && nv > 0.f) wb = (nv - cnt[c]) / fmaxf(nv, 1.f);
            const float em = (cnt[c] > 0.f) ? es[c] / fmaxf(cnt[c], 1.f) : 0.f;
            const float wc = wb * (1.f + LAMBDA_UNC * em);
            loss = fmaf(cs[c], wc, loss);
        }
        out[0] = loss / (nv + 1e-6f);
    }
}

extern "C" void kernel_launch(void* const* d_in, const int* in_sizes, int n_in,
                              void* d_out, int out_size, void* d_ws, size_t ws_size,
                              hipStream_t stream) {
    const float* logits = (const float*)d_in[0];
    const int* targets = (const int*)d_in[1];
    float* out = (float*)d_out;
    float* ws = (float*)d_ws;

    const size_t need = (size_t)30 * NBLOCKS * sizeof(float);   // 122,880 B
    if (ws_size >= need) {
        awce_main<false><<<NBLOCKS, THREADS, 0, stream>>>(logits, targets, ws);
        awce_final_partials<<<1, 512, 0, stream>>>(ws, out);
    } else {
        awce_zero_stats<<<1, 512, 0, stream>>>(ws);
        awce_main<true><<<NBLOCKS, THREADS, 0, stream>>>(logits, targets, ws);
        awce_final_atomic<<<1, 64, 0, stream>>>(ws, out);
    }
}